// Round 8
// baseline (324.741 us; speedup 1.0000x reference)
//
#include <hip/hip_runtime.h>
#include <stdint.h>
#include <stddef.h>

#define N_SENT 100000
#define N_TYPE 10000
#define NEDGE  640000
#define NROWS  (N_SENT + N_TYPE)
#define HB     128              // histogram chunks; 128 * 5000 == NEDGE
#define HCHUNK (NEDGE / HB)
#define NSLAB  8
#define SLABW  (N_SENT / NSLAB) // 12500 rows = 3.2 MB bf16 -> fits one XCD L2
#define TASKD  64               // dsts per work-stealing task
#define NTASKS ((N_TYPE + TASKD - 1) / TASKD)   // 157
#define AGG_BLOCKS 1280

__device__ __forceinline__ float bf2f(uint32_t lo16) {
    return __builtin_bit_cast(float, lo16 << 16);
}
__device__ __forceinline__ uint32_t f2bf(float f) {
    uint32_t u = __builtin_bit_cast(uint32_t, f);
    return (u + 0x7fffu + ((u >> 16) & 1u)) >> 16;
}
__device__ __forceinline__ bool detect_bf16(const uint32_t* __restrict__ h) {
    uint32_t u = h[threadIdx.x & 63];
    uint32_t e_lo = (u >> 7) & 0xffu;
    int ok = (e_lo >= 100u && e_lo <= 140u) ? 1 : 0;
    unsigned long long m = __ballot(ok);
    return __popcll(m) >= 48;
}
__device__ __forceinline__ int get_xcc() {
    int x;
    asm volatile("s_getreg_b32 %0, hwreg(HW_REG_XCC_ID)" : "=s"(x));
    return x & 7;
}

// ---- fused: per-row scores (16 rows/wave butterfly GEMV) + per-chunk LDS dst-histogram ----
#define SCORE_BLOCKS ((NROWS + 63) / 64)   // 1719

__global__ __launch_bounds__(256) void scores_count_k(const void* __restrict__ h_sent,
                                                      const void* __restrict__ h_type,
                                                      const void* __restrict__ attn_w,
                                                      const int* __restrict__ dst,
                                                      float* __restrict__ s_src,
                                                      float* __restrict__ s_dst,
                                                      uint32_t* __restrict__ count2) {
    __shared__ uint32_t hist[N_TYPE];   // 40 KB (count blocks only)
    int b = blockIdx.x;
    if (b < SCORE_BLOCKS) {
        int lane = threadIdx.x & 63;
        int r0   = (b * 4 + (int)(threadIdx.x >> 6)) * 16;
        bool isbf = detect_bf16((const uint32_t*)h_sent);
        float v[16];
        if (isbf) {
            uint32_t wv_s = ((const uint32_t*)attn_w)[lane];
            uint32_t wv_t = ((const uint32_t*)attn_w)[64 + lane];
            float ws0 = bf2f(wv_s & 0xffffu), ws1 = bf2f(wv_s >> 16);
            float wt0 = bf2f(wv_t & 0xffffu), wt1 = bf2f(wv_t >> 16);
#pragma unroll
            for (int i = 0; i < 16; i++) {
                int g = r0 + i;
                if (g >= NROWS) { v[i] = 0.0f; continue; }
                bool isSrc = g < N_SENT;
                const uint32_t* hp = isSrc
                    ? (const uint32_t*)h_sent + (size_t)g * 64
                    : (const uint32_t*)h_type + (size_t)(g - N_SENT) * 64;
                uint32_t hv = hp[lane];
                v[i] = isSrc ? (bf2f(hv & 0xffffu) * ws0 + bf2f(hv >> 16) * ws1)
                             : (bf2f(hv & 0xffffu) * wt0 + bf2f(hv >> 16) * wt1);
            }
        } else {
            float2 wv_s = ((const float2*)attn_w)[lane];
            float2 wv_t = ((const float2*)attn_w)[64 + lane];
#pragma unroll
            for (int i = 0; i < 16; i++) {
                int g = r0 + i;
                if (g >= NROWS) { v[i] = 0.0f; continue; }
                bool isSrc = g < N_SENT;
                const float2* hp = isSrc
                    ? (const float2*)h_sent + (size_t)g * 64
                    : (const float2*)h_type + (size_t)(g - N_SENT) * 64;
                float2 hv = hp[lane];
                v[i] = isSrc ? (hv.x * wv_s.x + hv.y * wv_s.y)
                             : (hv.x * wv_t.x + hv.y * wv_t.y);
            }
        }
        int b0 = lane & 1, b1 = (lane >> 1) & 1, b2 = (lane >> 2) & 1, b3 = (lane >> 3) & 1;
        float w_[8];
#pragma unroll
        for (int i = 0; i < 8; i++) {
            float keep = b0 ? v[2 * i + 1] : v[2 * i];
            float send = b0 ? v[2 * i]     : v[2 * i + 1];
            w_[i] = keep + __shfl_xor(send, 1, 64);
        }
        float x_[4];
#pragma unroll
        for (int i = 0; i < 4; i++) {
            float keep = b1 ? w_[2 * i + 1] : w_[2 * i];
            float send = b1 ? w_[2 * i]     : w_[2 * i + 1];
            x_[i] = keep + __shfl_xor(send, 2, 64);
        }
        float y_[2];
#pragma unroll
        for (int i = 0; i < 2; i++) {
            float keep = b2 ? x_[2 * i + 1] : x_[2 * i];
            float send = b2 ? x_[2 * i]     : x_[2 * i + 1];
            y_[i] = keep + __shfl_xor(send, 4, 64);
        }
        float z;
        {
            float keep = b3 ? y_[1] : y_[0];
            float send = b3 ? y_[0] : y_[1];
            z = keep + __shfl_xor(send, 8, 64);
        }
        z += __shfl_xor(z, 16, 64);
        z += __shfl_xor(z, 32, 64);
        if (lane < 16) {
            int g = r0 + lane;
            if (g < NROWS) {
                if (g < N_SENT) s_src[g] = z;
                else            s_dst[g - N_SENT] = z;
            }
        }
    } else {
        int cb = b - SCORE_BLOCKS;           // [0, HB)
        int t  = threadIdx.x;
        for (int i = t; i < N_TYPE; i += 256) hist[i] = 0u;
        __syncthreads();
        int e0 = cb * HCHUNK;
        for (int i = t; i < HCHUNK; i += 256)
            atomicAdd(&hist[dst[e0 + i]], 1u);
        __syncthreads();
        uint32_t* row = count2 + (size_t)cb * N_TYPE;
        for (int i = t; i < N_TYPE; i += 256) row[i] = hist[i];
    }
}

// ---- column exclusive-scan over chunks: count2 -> base2 (in place), total[bin] ----
__global__ __launch_bounds__(256) void sumscan_k(uint32_t* __restrict__ count2,
                                                 uint32_t* __restrict__ total) {
    int b = blockIdx.x * 256 + threadIdx.x;
    if (b >= N_TYPE) return;
    uint32_t run = 0;
#pragma unroll 4
    for (int c = 0; c < HB; c++) {
        uint32_t* p = count2 + (size_t)c * N_TYPE + b;
        uint32_t v = *p;
        *p = run;
        run += v;
    }
    total[b] = run;
}

// ---- single-block exclusive scan of totals -> offsets[N_TYPE+1]; also zero taskctr ----
__global__ __launch_bounds__(1024) void scan_k(const uint32_t* __restrict__ total,
                                               uint32_t* __restrict__ offsets,
                                               uint32_t* __restrict__ taskctr) {
    if (threadIdx.x < 8) taskctr[threadIdx.x] = 0u;
    const int CH = 10;
    int t = threadIdx.x, lane = t & 63, wv = t >> 6;
    int base = t * CH;
    uint32_t local[CH];
    uint32_t tsum = 0;
#pragma unroll
    for (int i = 0; i < CH; i++) {
        int idx = base + i;
        uint32_t c = (idx < N_TYPE) ? total[idx] : 0u;
        local[i] = c;
        tsum += c;
    }
    uint32_t orig = tsum;
#pragma unroll
    for (int off = 1; off < 64; off <<= 1) {
        uint32_t v = __shfl_up(tsum, off, 64);
        if (lane >= off) tsum += v;
    }
    __shared__ uint32_t wsum[16];
    if (lane == 63) wsum[wv] = tsum;
    __syncthreads();
    if (wv == 0 && lane < 16) {
        uint32_t u = wsum[lane], o = u;
#pragma unroll
        for (int off = 1; off < 16; off <<= 1) {
            uint32_t v = __shfl_up(u, off, 64);
            if (lane >= off) u += v;
        }
        wsum[lane] = u - o;
    }
    __syncthreads();
    uint32_t run = wsum[wv] + tsum - orig;
#pragma unroll
    for (int i = 0; i < CH; i++) {
        int idx = base + i;
        if (idx < N_TYPE) {
            offsets[idx] = run;
            run += local[i];
        } else if (idx == N_TYPE) {
            offsets[idx] = run;   // == NEDGE
        }
    }
}

// ---- fill: LDS cursors from offsets+base2; scatter (src, w=exp(lrelu(score))) by dst ----
__global__ __launch_bounds__(256) void fill_k(const int* __restrict__ src,
                                              const int* __restrict__ dst,
                                              const float* __restrict__ s_src,
                                              const float* __restrict__ s_dst,
                                              const uint32_t* __restrict__ offsets,
                                              const uint32_t* __restrict__ base2,
                                              uint2* __restrict__ edata) {
    __shared__ uint32_t cur[N_TYPE];   // 40 KB
    int cb = blockIdx.x;
    int t  = threadIdx.x;
    const uint32_t* brow = base2 + (size_t)cb * N_TYPE;
    for (int i = t; i < N_TYPE; i += 256) cur[i] = offsets[i] + brow[i];
    __syncthreads();
    int e0 = cb * HCHUNK;
    for (int i = t; i < HCHUNK; i += 256) {
        int e = e0 + i;
        int d = dst[e];
        int s = src[e];
        float v = s_src[s] + s_dst[d];
        v = v > 0.0f ? v : 0.01f * v;
        float w = __expf(v);                    // max-free softmax: |v| small, f32-safe
        uint32_t pos = atomicAdd(&cur[d], 1u);  // LDS-only atomic
        edata[pos] = make_uint2((uint32_t)s, __builtin_bit_cast(uint32_t, w));
    }
}

// ---- slabsort: one wave per dst; counting-sort segment by src-slab; emit segoff ----
__global__ __launch_bounds__(256) void slabsort_k(const uint32_t* __restrict__ offsets,
                                                  const uint2* __restrict__ edata,
                                                  uint2* __restrict__ edata2,
                                                  uint32_t* __restrict__ segoff) {
    int lane = threadIdx.x & 63;
    int j = (blockIdx.x * 256 + (int)threadIdx.x) >> 6;
    if (j >= N_TYPE) return;
    uint32_t beg = offsets[j], end = offsets[j + 1], deg = end - beg;
    // pass 1: per-slab counts (uniform across lanes)
    uint32_t cnt[NSLAB];
#pragma unroll
    for (int t = 0; t < NSLAB; t++) cnt[t] = 0u;
    for (uint32_t base = 0; base < deg; base += 64) {
        uint32_t k = base + lane;
        bool act = k < deg;
        uint32_t sv = act ? edata[beg + k].x : 0xffffffffu;
        uint32_t sl = act ? (sv / SLABW) : 8u;
#pragma unroll
        for (int t = 0; t < NSLAB; t++)
            cnt[t] += (uint32_t)__popcll(__ballot(sl == (uint32_t)t));
    }
    uint32_t start[NSLAB], run = 0;
#pragma unroll
    for (int t = 0; t < NSLAB; t++) { start[t] = run; run += cnt[t]; }
    uint32_t myseg = 0;
#pragma unroll
    for (int t = 0; t < NSLAB; t++) myseg = (lane == t) ? start[t] : myseg;
    if (lane < NSLAB) segoff[(size_t)j * NSLAB + lane] = beg + myseg;
    // pass 2: stable placement
    uint32_t cur[NSLAB];
#pragma unroll
    for (int t = 0; t < NSLAB; t++) cur[t] = start[t];
    unsigned long long lt = (lane == 63) ? 0x7fffffffffffffffull
                                         : ((1ull << lane) - 1ull);
    for (uint32_t base = 0; base < deg; base += 64) {
        uint32_t k = base + lane;
        bool act = k < deg;
        uint2 ed = act ? edata[beg + k] : make_uint2(0u, 0u);
        uint32_t sl = act ? (ed.x / SLABW) : 8u;
        uint32_t mypos = 0;
#pragma unroll
        for (int t = 0; t < NSLAB; t++) {
            unsigned long long mt = __ballot(sl == (uint32_t)t);
            uint32_t p = cur[t] + (uint32_t)__popcll(mt & lt);
            mypos = (sl == (uint32_t)t) ? p : mypos;
            cur[t] += (uint32_t)__popcll(mt);
        }
        if (act) edata2[beg + mypos] = ed;
    }
}

// ---- slab agg v2: persistent blocks, slab bound to the MEASURED XCD (work-stealing) ----
__global__ __launch_bounds__(256) void slab_agg_k(const void* __restrict__ h_sent,
                                                  const uint32_t* __restrict__ offsets,
                                                  const uint32_t* __restrict__ segoff,
                                                  const uint2* __restrict__ edata2,
                                                  uint32_t* __restrict__ taskctr,
                                                  uint32_t* __restrict__ pnum,
                                                  float* __restrict__ pden) {
    __shared__ uint32_t s_task;
    int lane = threadIdx.x & 63;
    int wv   = threadIdx.x >> 6;
    bool isbf = detect_bf16((const uint32_t*)h_sent);
    const uint32_t* hpb = (const uint32_t*)h_sent;
    const float2*   hpf = (const float2*)h_sent;
    int xcc = get_xcc();
    for (int att = 0; att < NSLAB; att++) {
        int slab = (xcc + att) & 7;   // own XCD's slab first; steal only when drained
        while (true) {
            if (threadIdx.x == 0) s_task = atomicAdd(&taskctr[slab], 1u);
            __syncthreads();
            uint32_t t = s_task;
            __syncthreads();
            if (t >= NTASKS) break;
            int j0 = (int)t * TASKD + wv * (TASKD / 4);
#pragma unroll 1
            for (int q = 0; q < TASKD / 4; q++) {
                int j = j0 + q;
                if (j >= N_TYPE) break;
                uint32_t off0 = segoff[(size_t)j * NSLAB + slab];
                uint32_t off1 = (slab < 7) ? segoff[(size_t)j * NSLAB + slab + 1]
                                           : offsets[j + 1];
                float a0 = 0.0f, a1 = 0.0f, ws = 0.0f;
                for (uint32_t bb = off0; bb < off1; bb += 8) {
                    uint32_t cnt = off1 - bb; if (cnt > 8u) cnt = 8u;
                    uint32_t idx = bb + (lane & 7);
                    if (idx >= off1) idx = off1 - 1;
                    uint2 ed = edata2[idx];
                    float wf = __builtin_bit_cast(float, ed.y);
                    if (isbf) {
#pragma unroll
                        for (int i = 0; i < 8; i++) {
                            uint32_t sb = __shfl(ed.x, i, 64);
                            float wb = (i < (int)cnt) ? __shfl(wf, i, 64) : 0.0f;
                            uint32_t gv = hpb[(size_t)sb * 64 + lane];
                            a0 += wb * bf2f(gv & 0xffffu);
                            a1 += wb * bf2f(gv >> 16);
                            ws += wb;
                        }
                    } else {
#pragma unroll
                        for (int i = 0; i < 8; i++) {
                            uint32_t sb = __shfl(ed.x, i, 64);
                            float wb = (i < (int)cnt) ? __shfl(wf, i, 64) : 0.0f;
                            float2 gv = hpf[(size_t)sb * 64 + lane];
                            a0 += wb * gv.x;
                            a1 += wb * gv.y;
                            ws += wb;
                        }
                    }
                }
                uint32_t row = (uint32_t)j * NSLAB + slab;
                pnum[(size_t)row * 64 + lane] = f2bf(a0) | (f2bf(a1) << 16);
                if (lane == 0) pden[row] = ws;   // ws identical on all lanes
            }
        }
    }
}

// ---- combine: sum 8 slab partials per dst, normalize; den==0 -> copy h_type ----
__global__ __launch_bounds__(256) void combine_k(const void* __restrict__ h_type,
                                                 const uint32_t* __restrict__ pnum,
                                                 const float* __restrict__ pden,
                                                 void* __restrict__ out) {
    int lane = threadIdx.x & 63;
    int j = (blockIdx.x * 256 + (int)threadIdx.x) >> 6;
    if (j >= N_TYPE) return;
    bool isbf = detect_bf16((const uint32_t*)h_type);
    float a0 = 0.0f, a1 = 0.0f, den = 0.0f;
#pragma unroll
    for (int s = 0; s < NSLAB; s++) {
        uint32_t row = (uint32_t)j * NSLAB + s;
        uint32_t v = pnum[(size_t)row * 64 + lane];
        a0 += bf2f(v & 0xffffu);
        a1 += bf2f(v >> 16);
        den += pden[row];
    }
    if (den > 0.0f) {
        float inv = 1.0f / den;
        if (isbf) ((uint32_t*)out)[(size_t)j * 64 + lane] = f2bf(a0 * inv) | (f2bf(a1 * inv) << 16);
        else      ((float2*)out)[(size_t)j * 64 + lane]   = make_float2(a0 * inv, a1 * inv);
    } else {
        if (isbf) ((uint32_t*)out)[(size_t)j * 64 + lane] = ((const uint32_t*)h_type)[(size_t)j * 64 + lane];
        else      ((float2*)out)[(size_t)j * 64 + lane]   = ((const float2*)h_type)[(size_t)j * 64 + lane];
    }
}

// ---- fallback plain agg (ws too small): max-free, register-broadcast over dst segment ----
__global__ __launch_bounds__(256) void plain_agg_k(const void* __restrict__ h_sent,
                                                   const void* __restrict__ h_type,
                                                   const uint32_t* __restrict__ offsets,
                                                   const uint2* __restrict__ edata,
                                                   void* __restrict__ out) {
    int lane = threadIdx.x & 63;
    int j = (blockIdx.x * 256 + (int)threadIdx.x) >> 6;
    if (j >= N_TYPE) return;
    bool isbf = detect_bf16((const uint32_t*)h_sent);
    uint32_t beg = offsets[j], end = offsets[j + 1];
    if (beg == end) {
        if (isbf) ((uint32_t*)out)[(size_t)j * 64 + lane] = ((const uint32_t*)h_type)[(size_t)j * 64 + lane];
        else      ((float2*)out)[(size_t)j * 64 + lane]   = ((const float2*)h_type)[(size_t)j * 64 + lane];
        return;
    }
    const uint32_t* hpb = (const uint32_t*)h_sent;
    const float2*   hpf = (const float2*)h_sent;
    float a0 = 0.0f, a1 = 0.0f, ws = 0.0f;
    for (uint32_t bb = beg; bb < end; bb += 8) {
        uint32_t cnt = end - bb; if (cnt > 8u) cnt = 8u;
        uint32_t idx = bb + (lane & 7);
        if (idx >= end) idx = end - 1;
        uint2 ed = edata[idx];
        float wf = __builtin_bit_cast(float, ed.y);
#pragma unroll
        for (int i = 0; i < 8; i++) {
            uint32_t sb = __shfl(ed.x, i, 64);
            float wb = (i < (int)cnt) ? __shfl(wf, i, 64) : 0.0f;
            if (isbf) {
                uint32_t gv = hpb[(size_t)sb * 64 + lane];
                a0 += wb * bf2f(gv & 0xffffu);
                a1 += wb * bf2f(gv >> 16);
            } else {
                float2 gv = hpf[(size_t)sb * 64 + lane];
                a0 += wb * gv.x;
                a1 += wb * gv.y;
            }
            ws += wb;
        }
    }
    float inv = 1.0f / ws;
    if (isbf) ((uint32_t*)out)[(size_t)j * 64 + lane] = f2bf(a0 * inv) | (f2bf(a1 * inv) << 16);
    else      ((float2*)out)[(size_t)j * 64 + lane]   = make_float2(a0 * inv, a1 * inv);
}

static inline size_t align_up(size_t x) { return (x + 255) & ~(size_t)255; }

extern "C" void kernel_launch(void* const* d_in, const int* in_sizes, int n_in,
                              void* d_out, int out_size, void* d_ws, size_t ws_size,
                              hipStream_t stream) {
    const void* h_sent = d_in[0];
    const void* h_type = d_in[1];
    const void* attn_w = d_in[2];
    const int* src_idx = (const int*)d_in[3];
    const int* dst_idx = (const int*)d_in[4];

    // region0: pnum (20.48 MB) overlays buffers that are dead before slab_agg writes it:
    //   s_src/s_dst (dead after fill), count2 (dead after fill), edata (dead after slabsort),
    //   total (dead after scan).
    char* base = (char*)d_ws;
    uint32_t* pnum   = (uint32_t*)base;
    float*    s_src  = (float*)base;                char* p = base + align_up((size_t)N_SENT * 4);
    float*    s_dst  = (float*)p;                   p += align_up((size_t)N_TYPE * 4);
    uint32_t* count2 = (uint32_t*)p;                p += align_up((size_t)HB * N_TYPE * 4);
    uint2*    edata  = (uint2*)p;                   p += align_up((size_t)NEDGE * 8);
    uint32_t* total  = (uint32_t*)p;                p += align_up((size_t)N_TYPE * 4);
    size_t region0_used = (size_t)(p - base);
    size_t region0 = align_up((size_t)N_TYPE * NSLAB * 64 * 4);   // 20.48 MB
    if (region0 < region0_used) region0 = align_up(region0_used);
    char* q = base + region0;
    uint32_t* offsets = (uint32_t*)q;  q += align_up((size_t)(N_TYPE + 1) * 4);
    uint32_t* segoff  = (uint32_t*)q;  q += align_up((size_t)N_TYPE * NSLAB * 4);
    uint2*    edata2  = (uint2*)q;     q += align_up((size_t)NEDGE * 8);
    float*    pden    = (float*)q;     q += align_up((size_t)N_TYPE * NSLAB * 4);
    uint32_t* taskctr = (uint32_t*)q;  q += 256;
    size_t need_slab  = (size_t)(q - base);                        // ~26.5 MB
    size_t need_plain = region0_used + align_up((size_t)(N_TYPE + 1) * 4) + 512;
    bool use_slab = ws_size >= need_slab;
    // if slab path is off, put offsets right after region0_used to fit small ws
    if (!use_slab) offsets = (uint32_t*)(base + region0_used);

    scores_count_k<<<SCORE_BLOCKS + HB, 256, 0, stream>>>(
        h_sent, h_type, attn_w, dst_idx, s_src, s_dst, count2);
    sumscan_k<<<(N_TYPE + 255) / 256, 256, 0, stream>>>(count2, total);
    scan_k<<<1, 1024, 0, stream>>>(total, offsets, use_slab ? taskctr : total);
    fill_k<<<HB, 256, 0, stream>>>(src_idx, dst_idx, s_src, s_dst, offsets, count2, edata);
    if (use_slab) {
        slabsort_k<<<(N_TYPE + 3) / 4, 256, 0, stream>>>(offsets, edata, edata2, segoff);
        slab_agg_k<<<AGG_BLOCKS, 256, 0, stream>>>(h_sent, offsets, segoff, edata2,
                                                   taskctr, pnum, pden);
        combine_k<<<(N_TYPE + 3) / 4, 256, 0, stream>>>(h_type, pnum, pden, d_out);
    } else {
        (void)need_plain;
        plain_agg_k<<<(N_TYPE + 3) / 4, 256, 0, stream>>>(h_sent, h_type, offsets, edata, d_out);
    }
}

// Round 9
// 199.275 us; speedup vs baseline: 1.6296x; 1.6296x over previous
//
#include <hip/hip_runtime.h>
#include <stdint.h>
#include <stddef.h>

#define N_SENT 100000
#define N_TYPE 10000
#define NEDGE  640000
#define NROWS  (N_SENT + N_TYPE)
#define HB     128              // histogram chunks; 128 * 5000 == NEDGE
#define HCHUNK (NEDGE / HB)

__device__ __forceinline__ float bf2f(uint32_t lo16) {
    return __builtin_bit_cast(float, lo16 << 16);
}
__device__ __forceinline__ uint32_t f2bf(float f) {
    uint32_t u = __builtin_bit_cast(uint32_t, f);
    return (u + 0x7fffu + ((u >> 16) & 1u)) >> 16;
}
// bf16 pairs have bf16-sane exponents in the low halfword; f32 low halfwords are
// mantissa bits (uniform). One broadcast load + ballot, wave-uniform result.
__device__ __forceinline__ bool detect_bf16(const uint32_t* __restrict__ h) {
    uint32_t u = h[threadIdx.x & 63];
    uint32_t e_lo = (u >> 7) & 0xffu;
    int ok = (e_lo >= 100u && e_lo <= 140u) ? 1 : 0;
    unsigned long long m = __ballot(ok);
    return __popcll(m) >= 48;
}

// ---- fused: per-row scores (16 rows/wave butterfly GEMV) + per-chunk LDS dst-histogram ----
#define SCORE_BLOCKS ((NROWS + 63) / 64)   // 1719

__global__ __launch_bounds__(256) void scores_count_k(const void* __restrict__ h_sent,
                                                      const void* __restrict__ h_type,
                                                      const void* __restrict__ attn_w,
                                                      const int* __restrict__ dst,
                                                      float* __restrict__ s_src,
                                                      float* __restrict__ s_dst,
                                                      uint32_t* __restrict__ count2) {
    __shared__ uint32_t hist[N_TYPE];   // 40 KB (count blocks only)
    int b = blockIdx.x;
    if (b < SCORE_BLOCKS) {
        int lane = threadIdx.x & 63;
        int r0   = (b * 4 + (int)(threadIdx.x >> 6)) * 16;
        bool isbf = detect_bf16((const uint32_t*)h_sent);
        float v[16];
        if (isbf) {
            uint32_t wv_s = ((const uint32_t*)attn_w)[lane];
            uint32_t wv_t = ((const uint32_t*)attn_w)[64 + lane];
            float ws0 = bf2f(wv_s & 0xffffu), ws1 = bf2f(wv_s >> 16);
            float wt0 = bf2f(wv_t & 0xffffu), wt1 = bf2f(wv_t >> 16);
#pragma unroll
            for (int i = 0; i < 16; i++) {
                int g = r0 + i;
                if (g >= NROWS) { v[i] = 0.0f; continue; }
                bool isSrc = g < N_SENT;
                const uint32_t* hp = isSrc
                    ? (const uint32_t*)h_sent + (size_t)g * 64
                    : (const uint32_t*)h_type + (size_t)(g - N_SENT) * 64;
                uint32_t hv = hp[lane];
                v[i] = isSrc ? (bf2f(hv & 0xffffu) * ws0 + bf2f(hv >> 16) * ws1)
                             : (bf2f(hv & 0xffffu) * wt0 + bf2f(hv >> 16) * wt1);
            }
        } else {
            float2 wv_s = ((const float2*)attn_w)[lane];
            float2 wv_t = ((const float2*)attn_w)[64 + lane];
#pragma unroll
            for (int i = 0; i < 16; i++) {
                int g = r0 + i;
                if (g >= NROWS) { v[i] = 0.0f; continue; }
                bool isSrc = g < N_SENT;
                const float2* hp = isSrc
                    ? (const float2*)h_sent + (size_t)g * 64
                    : (const float2*)h_type + (size_t)(g - N_SENT) * 64;
                float2 hv = hp[lane];
                v[i] = isSrc ? (hv.x * wv_s.x + hv.y * wv_s.y)
                             : (hv.x * wv_t.x + hv.y * wv_t.y);
            }
        }
        // fold 16 rows -> 1 value/lane (row = lane&15): merge d=1,2,4,8 then butterfly
        int b0 = lane & 1, b1 = (lane >> 1) & 1, b2 = (lane >> 2) & 1, b3 = (lane >> 3) & 1;
        float w_[8];
#pragma unroll
        for (int i = 0; i < 8; i++) {
            float keep = b0 ? v[2 * i + 1] : v[2 * i];
            float send = b0 ? v[2 * i]     : v[2 * i + 1];
            w_[i] = keep + __shfl_xor(send, 1, 64);
        }
        float x_[4];
#pragma unroll
        for (int i = 0; i < 4; i++) {
            float keep = b1 ? w_[2 * i + 1] : w_[2 * i];
            float send = b1 ? w_[2 * i]     : w_[2 * i + 1];
            x_[i] = keep + __shfl_xor(send, 2, 64);
        }
        float y_[2];
#pragma unroll
        for (int i = 0; i < 2; i++) {
            float keep = b2 ? x_[2 * i + 1] : x_[2 * i];
            float send = b2 ? x_[2 * i]     : x_[2 * i + 1];
            y_[i] = keep + __shfl_xor(send, 4, 64);
        }
        float z;
        {
            float keep = b3 ? y_[1] : y_[0];
            float send = b3 ? y_[0] : y_[1];
            z = keep + __shfl_xor(send, 8, 64);
        }
        z += __shfl_xor(z, 16, 64);
        z += __shfl_xor(z, 32, 64);
        if (lane < 16) {
            int g = r0 + lane;
            if (g < NROWS) {
                if (g < N_SENT) s_src[g] = z;
                else            s_dst[g - N_SENT] = z;
            }
        }
    } else {
        int cb = b - SCORE_BLOCKS;           // [0, HB)
        int t  = threadIdx.x;
        for (int i = t; i < N_TYPE; i += 256) hist[i] = 0u;
        __syncthreads();
        int e0 = cb * HCHUNK;
        for (int i = t; i < HCHUNK; i += 256)
            atomicAdd(&hist[dst[e0 + i]], 1u);
        __syncthreads();
        uint32_t* row = count2 + (size_t)cb * N_TYPE;
        for (int i = t; i < N_TYPE; i += 256) row[i] = hist[i];
    }
}

// ---- column exclusive-scan over chunks: count2 -> base2 (in place), total[bin] ----
__global__ __launch_bounds__(256) void sumscan_k(uint32_t* __restrict__ count2,
                                                 uint32_t* __restrict__ total) {
    int b = blockIdx.x * 256 + threadIdx.x;
    if (b >= N_TYPE) return;
    uint32_t run = 0;
#pragma unroll 8
    for (int c = 0; c < HB; c++) {
        uint32_t* p = count2 + (size_t)c * N_TYPE + b;
        uint32_t v = *p;
        *p = run;
        run += v;
    }
    total[b] = run;
}

// ---- single-block exclusive scan of totals -> offsets[N_TYPE+1] ----
__global__ __launch_bounds__(1024) void scan_k(const uint32_t* __restrict__ total,
                                               uint32_t* __restrict__ offsets) {
    const int CH = 10;
    int t = threadIdx.x, lane = t & 63, wv = t >> 6;
    int base = t * CH;
    uint32_t local[CH];
    uint32_t tsum = 0;
#pragma unroll
    for (int i = 0; i < CH; i++) {
        int idx = base + i;
        uint32_t c = (idx < N_TYPE) ? total[idx] : 0u;
        local[i] = c;
        tsum += c;
    }
    uint32_t orig = tsum;
#pragma unroll
    for (int off = 1; off < 64; off <<= 1) {
        uint32_t v = __shfl_up(tsum, off, 64);
        if (lane >= off) tsum += v;
    }
    __shared__ uint32_t wsum[16];
    if (lane == 63) wsum[wv] = tsum;
    __syncthreads();
    if (wv == 0 && lane < 16) {
        uint32_t u = wsum[lane], o = u;
#pragma unroll
        for (int off = 1; off < 16; off <<= 1) {
            uint32_t v = __shfl_up(u, off, 64);
            if (lane >= off) u += v;
        }
        wsum[lane] = u - o;
    }
    __syncthreads();
    uint32_t run = wsum[wv] + tsum - orig;
#pragma unroll
    for (int i = 0; i < CH; i++) {
        int idx = base + i;
        if (idx < N_TYPE) {
            offsets[idx] = run;
            run += local[i];
        } else if (idx == N_TYPE) {
            offsets[idx] = run;   // == NEDGE
        }
    }
}

// ---- fill: LDS cursors from offsets+base2; scatter (src, w=exp(lrelu(score))) by dst ----
__global__ __launch_bounds__(256) void fill_k(const int* __restrict__ src,
                                              const int* __restrict__ dst,
                                              const float* __restrict__ s_src,
                                              const float* __restrict__ s_dst,
                                              const uint32_t* __restrict__ offsets,
                                              const uint32_t* __restrict__ base2,
                                              uint2* __restrict__ edata) {
    __shared__ uint32_t cur[N_TYPE];   // 40 KB
    int cb = blockIdx.x;
    int t  = threadIdx.x;
    const uint32_t* brow = base2 + (size_t)cb * N_TYPE;
    for (int i = t; i < N_TYPE; i += 256) cur[i] = offsets[i] + brow[i];
    __syncthreads();
    int e0 = cb * HCHUNK;
    for (int i = t; i < HCHUNK; i += 256) {
        int e = e0 + i;
        int d = dst[e];
        int s = src[e];
        float v = s_src[s] + s_dst[d];
        v = v > 0.0f ? v : 0.01f * v;
        float w = __expf(v);                    // max-free softmax: |v| small, f32-safe
        uint32_t pos = atomicAdd(&cur[d], 1u);  // LDS-only atomic
        edata[pos] = make_uint2((uint32_t)s, __builtin_bit_cast(uint32_t, w));
    }
}

// ---- agg v3: one wave per dst. LDS-free, max-free. Wave-uniform edata loads
//      (sequential, L1/L2-friendly) + 8 independent row gathers in flight. ----
__global__ __launch_bounds__(256) void agg_k(const void* __restrict__ h_sent,
                                             const void* __restrict__ h_type,
                                             const uint32_t* __restrict__ offsets,
                                             const uint2* __restrict__ edata,
                                             void* __restrict__ out) {
    int lane = threadIdx.x & 63;
    int j = (blockIdx.x * 256 + (int)threadIdx.x) >> 6;
    if (j >= N_TYPE) return;
    bool isbf = detect_bf16((const uint32_t*)h_sent);
    uint32_t beg = offsets[j], end = offsets[j + 1];
    if (beg == end) {   // isolated node keeps its input feature
        if (isbf) ((uint32_t*)out)[(size_t)j * 64 + lane] =
                      ((const uint32_t*)h_type)[(size_t)j * 64 + lane];
        else      ((float2*)out)[(size_t)j * 64 + lane] =
                      ((const float2*)h_type)[(size_t)j * 64 + lane];
        return;
    }
    float a0 = 0.0f, a1 = 0.0f, den = 0.0f;
    if (isbf) {
        const uint32_t* hp = (const uint32_t*)h_sent;
        uint32_t k = beg;
        for (; k + 8 <= end; k += 8) {
            uint2 ed[8];
#pragma unroll
            for (int i = 0; i < 8; i++) ed[i] = edata[k + i];       // uniform loads
            uint32_t gv[8];
#pragma unroll
            for (int i = 0; i < 8; i++) gv[i] = hp[(size_t)ed[i].x * 64 + lane];
#pragma unroll
            for (int i = 0; i < 8; i++) {
                float w = __builtin_bit_cast(float, ed[i].y);
                den += w;
                a0 += w * bf2f(gv[i] & 0xffffu);
                a1 += w * bf2f(gv[i] >> 16);
            }
        }
        for (; k < end; ++k) {
            uint2 ed = edata[k];
            uint32_t gv = hp[(size_t)ed.x * 64 + lane];
            float w = __builtin_bit_cast(float, ed.y);
            den += w;
            a0 += w * bf2f(gv & 0xffffu);
            a1 += w * bf2f(gv >> 16);
        }
        float inv = 1.0f / den;
        ((uint32_t*)out)[(size_t)j * 64 + lane] = f2bf(a0 * inv) | (f2bf(a1 * inv) << 16);
    } else {
        const float2* hp = (const float2*)h_sent;
        uint32_t k = beg;
        for (; k + 8 <= end; k += 8) {
            uint2 ed[8];
#pragma unroll
            for (int i = 0; i < 8; i++) ed[i] = edata[k + i];
            float2 gv[8];
#pragma unroll
            for (int i = 0; i < 8; i++) gv[i] = hp[(size_t)ed[i].x * 64 + lane];
#pragma unroll
            for (int i = 0; i < 8; i++) {
                float w = __builtin_bit_cast(float, ed[i].y);
                den += w;
                a0 += w * gv[i].x;
                a1 += w * gv[i].y;
            }
        }
        for (; k < end; ++k) {
            uint2 ed = edata[k];
            float2 gv = hp[(size_t)ed.x * 64 + lane];
            float w = __builtin_bit_cast(float, ed.y);
            den += w;
            a0 += w * gv.x;
            a1 += w * gv.y;
        }
        float inv = 1.0f / den;
        ((float2*)out)[(size_t)j * 64 + lane] = make_float2(a0 * inv, a1 * inv);
    }
}

static inline size_t align_up(size_t x) { return (x + 255) & ~(size_t)255; }

extern "C" void kernel_launch(void* const* d_in, const int* in_sizes, int n_in,
                              void* d_out, int out_size, void* d_ws, size_t ws_size,
                              hipStream_t stream) {
    const void* h_sent = d_in[0];
    const void* h_type = d_in[1];
    const void* attn_w = d_in[2];
    const int* src_idx = (const int*)d_in[3];
    const int* dst_idx = (const int*)d_in[4];

    char* w = (char*)d_ws;
    float*    s_src   = (float*)w;    w += align_up((size_t)N_SENT * 4);
    float*    s_dst   = (float*)w;    w += align_up((size_t)N_TYPE * 4);
    uint32_t* count2  = (uint32_t*)w; w += align_up((size_t)HB * N_TYPE * 4);   // 5.12 MB
    uint32_t* total   = (uint32_t*)w; w += align_up((size_t)N_TYPE * 4);
    uint32_t* offsets = (uint32_t*)w; w += align_up((size_t)(N_TYPE + 1) * 4);
    uint2*    edata   = (uint2*)w;    w += align_up((size_t)NEDGE * 8);         // 5.12 MB
    // total ~10.8 MB (r8 confirmed ws_size >= 26.5 MB on this harness)

    scores_count_k<<<SCORE_BLOCKS + HB, 256, 0, stream>>>(
        h_sent, h_type, attn_w, dst_idx, s_src, s_dst, count2);
    sumscan_k<<<(N_TYPE + 255) / 256, 256, 0, stream>>>(count2, total);
    scan_k<<<1, 1024, 0, stream>>>(total, offsets);
    fill_k<<<HB, 256, 0, stream>>>(src_idx, dst_idx, s_src, s_dst, offsets, count2, edata);
    agg_k<<<(N_TYPE + 3) / 4, 256, 0, stream>>>(h_sent, h_type, offsets, edata, d_out);
}